// Round 10
// baseline (175.530 us; speedup 1.0000x reference)
//
#include <hip/hip_runtime.h>

#define B_    1024
#define TI_   2
#define TE_   3
#define AB_   (TI_ * TE_)
#define BIN_  16
#define BOUT_ 32

typedef float f4 __attribute__((ext_vector_type(4)));

// out[slice, o, l, k] = sum_i X[slice, i, l] * W[ab, i, o, k]
//
// R10: ONE kernel, all degrees. R7/R8/R9 (three different inner structures)
// all plateaued at ~150us -> the shared limiter is the 5 serialized launches
// (per-kernel BW ramps + tails + gaps), not the inner loop. Fusing lets the
// small degrees execute in the l8/l6 tail: continuous occupancy, no gaps.
//
// R2's fusion failure (shared-regalloc VGPR squeeze -> VALU-bound) is avoided:
// each degree is a __noinline__ device function = own register allocation and
// scheduling; zero LDS so no generic-pointer pessimization crosses the call.
//
// Per degree (R9 structure): thread = (slice, o, k-quad). X row-set lives
// wave-spread in <=5 VGPRs, fetched per (i,l) with compile-time v_readlane.
// W hoisted (16 x f4). acc[NSH] f4 stored directly as 16B global stores
// (4B-aligned legal); tail quads overlap (k0 = min(4q, NSH-4)) -> duplicate
// threads store identical bytes, benign, HBM sees each line once (R2/R3
// counters: WRITE_SIZE stayed exactly ideal with non-contiguous stores).
template<int NSH, int QTP, int SPB, int BLOCK>
__device__ __noinline__ void conv_deg(const float* __restrict__ X,
                                      const float* __restrict__ W,
                                      float* __restrict__ OUT, int bi) {
    constexpr int TS   = 32 * QTP;        // threads per slice (wave multiple)
    constexpr int SZ   = BIN_ * NSH;      // X floats per slice
    constexpr int XR   = (SZ + 63) / 64;  // wave-spread X VGPRs
    constexpr int NOUT = BOUT_ * NSH * NSH;
    static_assert(TS % 64 == 0, "wave-aligned slices (readlane uniformity)");
    static_assert(SPB * TS == BLOCK, "no idle threads");

    const int tid  = threadIdx.x;
    const int lane = tid & 63;
    const int sl   = tid / TS;            // wave-uniform
    const int wid  = tid - sl * TS;
    const int o    = wid / QTP;
    const int q    = wid - o * QTP;
    const int k0   = (4 * q > NSH - 4) ? (NSH - 4) : (4 * q);
    const int slice = bi * SPB + sl;
    const int ab    = slice % AB_;

    // X row-set -> wave-spread VGPRs (coalesced; clamped slots never read)
    const float* Xs = X + (size_t)slice * SZ;
    float xr[XR];
#pragma unroll
    for (int c = 0; c < XR; ++c) {
        int idx = c * 64 + lane;
        if (idx > SZ - 1) idx = SZ - 1;
        xr[c] = Xs[idx];
    }

    // hoist W (this thread's k-quad, all i)
    const float* Wp = W + (size_t)ab * (BIN_ * BOUT_ * NSH) + o * NSH + k0;
    f4 wreg[BIN_];
#pragma unroll
    for (int i = 0; i < BIN_; ++i)
        __builtin_memcpy(&wreg[i], Wp + (size_t)i * (BOUT_ * NSH), 16);

    f4 acc[NSH];
#pragma unroll
    for (int l = 0; l < NSH; ++l) acc[l] = (f4){0.f, 0.f, 0.f, 0.f};

#pragma unroll
    for (int i = 0; i < BIN_; ++i) {
#pragma unroll
        for (int l = 0; l < NSH; ++l) {
            const int idx = i * NSH + l;                    // compile-time
            const float xv = __int_as_float(
                __builtin_amdgcn_readlane(__float_as_int(xr[idx >> 6]),
                                          idx & 63));
            const f4 xb = {xv, xv, xv, xv};
            acc[l] = __builtin_elementwise_fma(xb, wreg[i], acc[l]);
        }
    }

    // direct 16B stores (duplicate quads store identical bytes; benign)
    float* Op = OUT + (size_t)slice * NOUT + o * (NSH * NSH) + k0;
#pragma unroll
    for (int l = 0; l < NSH; ++l)
        __builtin_memcpy(Op + l * NSH, &acc[l], 16);
}

// l=0: flat element map, fully coalesced dword stores.
__device__ __noinline__ void conv_l0(const float* __restrict__ X,
                                     const float* __restrict__ W,
                                     const float* __restrict__ bias,
                                     float* __restrict__ OUT, int bi) {
    const int elem  = bi * 384 + threadIdx.x;   // grid sized exactly
    const int slice = elem >> 5;
    const int o     = elem & 31;
    const int ab    = slice % AB_;
    const float* Xp = X + (size_t)slice * BIN_;
    float acc = bias[ab * BOUT_ + o];
#pragma unroll
    for (int i = 0; i < BIN_; ++i)
        acc = fmaf(Xp[i], W[(ab * BIN_ + i) * BOUT_ + o], acc);
    OUT[elem] = acc;
}

#define NB8 3072   // 6144 slices / SPB 2
#define NB6 2048   // / 3
#define NB4 2048   // / 3
#define NB2 1024   // / 6
#define NB0 512    // 196608 elems / 384

__global__ __launch_bounds__(384, 1)
void s2conv_all(const float* __restrict__ x0, const float* __restrict__ x2,
                const float* __restrict__ x4, const float* __restrict__ x6,
                const float* __restrict__ x8,
                const float* __restrict__ w0, const float* __restrict__ w2,
                const float* __restrict__ w4, const float* __restrict__ w6,
                const float* __restrict__ w8,
                const float* __restrict__ bias, float* __restrict__ out,
                size_t off0, size_t off2, size_t off4, size_t off6, size_t off8) {
    int b = blockIdx.x;                       // big degrees first
    if (b < NB8) { conv_deg<17, 6, 2, 384>(x8, w8, out + off8, b); return; }
    b -= NB8;
    if (b < NB6) { conv_deg<13, 4, 3, 384>(x6, w6, out + off6, b); return; }
    b -= NB6;
    if (b < NB4) { conv_deg< 9, 4, 3, 384>(x4, w4, out + off4, b); return; }
    b -= NB4;
    if (b < NB2) { conv_deg< 5, 2, 6, 384>(x2, w2, out + off2, b); return; }
    b -= NB2;
    conv_l0(x0, w0, bias, out + off0, b);
}

extern "C" void kernel_launch(void* const* d_in, const int* in_sizes, int n_in,
                              void* d_out, int out_size, void* d_ws, size_t ws_size,
                              hipStream_t stream) {
    const float* x0 = (const float*)d_in[0];
    const float* w0 = (const float*)d_in[1];
    const float* x2 = (const float*)d_in[2];
    const float* w2 = (const float*)d_in[3];
    const float* x4 = (const float*)d_in[4];
    const float* w4 = (const float*)d_in[5];
    const float* x6 = (const float*)d_in[6];
    const float* w6 = (const float*)d_in[7];
    const float* x8 = (const float*)d_in[8];
    const float* w8 = (const float*)d_in[9];
    const float* bias = (const float*)d_in[10];
    float* out = (float*)d_out;

    const size_t per = (size_t)B_ * AB_ * BOUT_;
    size_t off0 = 0;
    size_t off2 = off0 + per * 1;
    size_t off4 = off2 + per * 25;
    size_t off6 = off4 + per * 81;
    size_t off8 = off6 + per * 169;

    const int nblocks = NB8 + NB6 + NB4 + NB2 + NB0;   // 8704
    s2conv_all<<<nblocks, 384, 0, stream>>>(x0, x2, x4, x6, x8,
                                            w0, w2, w4, w6, w8,
                                            bias, out,
                                            off0, off2, off4, off6, off8);
}